// Round 1
// baseline (953.447 us; speedup 1.0000x reference)
//
#include <hip/hip_runtime.h>

#define B    16384
#define G    128
#define SMAX 64
#define H    10
#define PH   100

// ---------------------------------------------------------------------------
// Kernel 1: per-gene MLP -> gene_layer, stored TRANSPOSED glT[g][b] so the
// wave's store is 256B contiguous (layout [b][g] would be a scattered 4B/lane
// write with ~16x write amplification).
// Grid: (B/256, G). Block: 256 threads, one gene per block.
// ---------------------------------------------------------------------------
__global__ __launch_bounds__(256) void gene_kernel(
    const float* __restrict__ x,  const float* __restrict__ W1,
    const float* __restrict__ b1, const float* __restrict__ W2,
    const float* __restrict__ b2, float* __restrict__ glT)
{
    __shared__ float sW1[SMAX * H];   // 640 floats = 2.5 KiB
    __shared__ float sb1[H];
    __shared__ float sW2[H];
    __shared__ float sb2;

    const int tid = threadIdx.x;
    const int g   = blockIdx.y;
    const int b   = blockIdx.x * 256 + tid;

    // Issue the x-row loads first: 16 float4 = 256B contiguous per lane,
    // every fetched 64B line fully consumed.
    const float4* xr = (const float4*)(x + ((size_t)b * G + g) * SMAX);
    float4 xv[16];
    #pragma unroll
    for (int i = 0; i < 16; i++) xv[i] = xr[i];

    // Stage the per-gene params into LDS (W1_g = 640 floats).
    if (tid < 160) {
        ((float4*)sW1)[tid] = ((const float4*)(W1 + (size_t)g * SMAX * H))[tid];
    } else if (tid < 170) {
        sb1[tid - 160] = b1[g * H + (tid - 160)];
    } else if (tid < 180) {
        sW2[tid - 170] = W2[g * H + (tid - 170)];
    } else if (tid == 180) {
        sb2 = b2[g];
    }
    __syncthreads();

    // h[j] = relu(sum_s x[s]*W1[s][j] + b1[j]), j=0..9, kept as 5 float2 accs.
    float2 acc[5];
    #pragma unroll
    for (int j = 0; j < 5; j++) acc[j] = make_float2(sb1[2 * j], sb1[2 * j + 1]);

    const float2* w2p = (const float2*)sW1;   // row s = 5 float2 (8B aligned)
    #pragma unroll
    for (int s = 0; s < SMAX; s++) {
        const float xs = ((const float*)xv)[s];   // static index (unrolled)
        #pragma unroll
        for (int j = 0; j < 5; j++) {
            const float2 w = w2p[s * 5 + j];      // wave-uniform -> LDS broadcast
            acc[j].x = fmaf(xs, w.x, acc[j].x);
            acc[j].y = fmaf(xs, w.y, acc[j].y);
        }
    }

    // gene_layer = h . W2 + b2   (no relu on this one)
    float gene = sb2;
    #pragma unroll
    for (int j = 0; j < 5; j++) {
        gene += fmaxf(acc[j].x, 0.f) * sW2[2 * j]
              + fmaxf(acc[j].y, 0.f) * sW2[2 * j + 1];
    }

    glT[(size_t)g * B + b] = gene;   // coalesced: lanes b consecutive
}

// ---------------------------------------------------------------------------
// Kernel 2: predictor. lane = hidden unit j (128 lanes, j>=100 predicated),
// block handles 8 batch rows. gene rows LDS-broadcast, Wp1 column in regs.
// Grid: B/8 = 2048 blocks. Block: 128 threads (2 waves).
// ---------------------------------------------------------------------------
__global__ __launch_bounds__(128) void pred_kernel(
    const float* __restrict__ glT, const float* __restrict__ Wp1,
    const float* __restrict__ bp1, const float* __restrict__ Wp2,
    const float* __restrict__ bp2, float* __restrict__ out)
{
    __shared__ float sgl[8 * G];     // [b_local][g], 4 KiB
    __shared__ float sred[2][8];

    const int tid = threadIdx.x;     // j = tid
    const int b0  = blockIdx.x * 8;

    // Stage glT[g = tid][b0 .. b0+7] -> sgl[b][g]
    {
        const float4* gp = (const float4*)(glT + (size_t)tid * B + b0);
        const float4 v0 = gp[0], v1 = gp[1];
        sgl[0 * G + tid] = v0.x; sgl[1 * G + tid] = v0.y;
        sgl[2 * G + tid] = v0.z; sgl[3 * G + tid] = v0.w;
        sgl[4 * G + tid] = v1.x; sgl[5 * G + tid] = v1.y;
        sgl[6 * G + tid] = v1.z; sgl[7 * G + tid] = v1.w;
    }

    const bool  jv   = (tid < PH);
    const float bpj  = jv ? bp1[tid] : 0.f;
    const float wp2j = jv ? Wp2[tid] : 0.f;
    __syncthreads();

    float acc[8];
    #pragma unroll
    for (int b = 0; b < 8; b++) acc[b] = bpj;

    const float2* sgl2 = (const float2*)sgl;
    #pragma unroll
    for (int gc = 0; gc < 4; gc++) {
        // Wp1 column j for 32 genes, held in regs. Natural [G,PH] layout is
        // lane-contiguous in j -> coalesced loads.
        float2 w[16];
        #pragma unroll
        for (int p = 0; p < 16; p++) {
            const int gg = gc * 32 + 2 * p;
            w[p].x = jv ? Wp1[(size_t)gg * PH + tid]       : 0.f;
            w[p].y = jv ? Wp1[(size_t)(gg + 1) * PH + tid] : 0.f;
        }
        #pragma unroll
        for (int b = 0; b < 8; b++) {
            float a = acc[b];
            #pragma unroll
            for (int p = 0; p < 16; p++) {
                const float2 s2 = sgl2[b * (G / 2) + gc * 16 + p]; // broadcast
                a = fmaf(w[p].x, s2.x, a);
                a = fmaf(w[p].y, s2.y, a);
            }
            acc[b] = a;
        }
    }

    // out[b] = sum_j relu(acc_j) * Wp2[j] + bp2
    const int lane = tid & 63;
    const int wv   = tid >> 6;
    #pragma unroll
    for (int b = 0; b < 8; b++) {
        float v = fmaxf(acc[b], 0.f) * wp2j;
        #pragma unroll
        for (int off = 32; off > 0; off >>= 1) v += __shfl_down(v, off, 64);
        if (lane == 0) sred[wv][b] = v;
    }
    __syncthreads();
    if (tid < 8) out[b0 + tid] = sred[0][tid] + sred[1][tid] + bp2[0];
}

extern "C" void kernel_launch(void* const* d_in, const int* in_sizes, int n_in,
                              void* d_out, int out_size, void* d_ws, size_t ws_size,
                              hipStream_t stream) {
    const float* x   = (const float*)d_in[0];
    const float* W1  = (const float*)d_in[1];
    const float* b1  = (const float*)d_in[2];
    const float* W2  = (const float*)d_in[3];
    const float* b2  = (const float*)d_in[4];
    const float* Wp1 = (const float*)d_in[5];
    const float* bp1 = (const float*)d_in[6];
    const float* Wp2 = (const float*)d_in[7];
    const float* bp2 = (const float*)d_in[8];
    float* out = (float*)d_out;
    float* glT = (float*)d_ws;   // G*B floats = 8 MiB scratch

    gene_kernel<<<dim3(B / 256, G), 256, 0, stream>>>(x, W1, b1, W2, b2, glT);
    pred_kernel<<<dim3(B / 8), 128, 0, stream>>>(glT, Wp1, bp1, Wp2, bp2, out);
}